// Round 1
// baseline (909.206 us; speedup 1.0000x reference)
//
#include <hip/hip_runtime.h>
#include <hip/hip_bf16.h>

// Problem constants (from reference)
#define N_SINGLE 24
#define N_MULTI 8
#define MULTI_LEN 20
#define N_FEAT (N_SINGLE + N_MULTI)       // 32
#define VOCAB 100000
#define EMB 64
#define BATCH 4096
#define TOTAL_W (N_SINGLE + N_MULTI * MULTI_LEN)  // 184

// Each output token (b, f) is one row of 64 floats = 16 float4.
// A 16-lane group handles one token; lane i loads float4 #i of the row.
// Wave64 = 4 consecutive tokens -> feature ids within a wave are
// {4k..4k+3}, so the single/multi branch is wave-uniform (24 % 4 == 0).
__global__ __launch_bounds__(256) void feb_kernel(
    const int* __restrict__ feats,     // (BATCH, TOTAL_W)
    const float4* __restrict__ W,      // (N_FEAT, VOCAB+1, EMB) viewed as float4[... , 16]
    float4* __restrict__ out)          // (BATCH, N_FEAT, EMB) viewed as float4[..., 16]
{
    const int tok  = blockIdx.x * (blockDim.x >> 4) + (threadIdx.x >> 4);
    const int lane = threadIdx.x & 15;
    if (tok >= BATCH * N_FEAT) return;

    const int b = tok >> 5;        // / N_FEAT (=32)
    const int f = tok & 31;        // % N_FEAT

    const int* __restrict__ row = feats + (size_t)b * TOTAL_W;
    const size_t w_feat_base = (size_t)f * (size_t)(VOCAB + 1) * 16;  // float4 units

    if (f < N_SINGLE) {
        int idx = row[f];
        idx = min(max(idx, 0), VOCAB);
        out[(size_t)tok * 16 + lane] = W[w_feat_base + (size_t)idx * 16 + lane];
    } else {
        const int j = f - N_SINGLE;
        const int* __restrict__ mrow = row + N_SINGLE + j * MULTI_LEN;

        // Load the 20 indices first (scalar, L1-broadcast across the group),
        // then issue all 20 row gathers back-to-back for MLP.
        int idxs[MULTI_LEN];
        int cnt = 0;
#pragma unroll
        for (int t = 0; t < MULTI_LEN; ++t) {
            int v = mrow[t];
            v = min(max(v, 0), VOCAB);
            idxs[t] = v;
            cnt += (v != 0);
        }

        float4 acc = make_float4(0.f, 0.f, 0.f, 0.f);
#pragma unroll
        for (int t = 0; t < MULTI_LEN; ++t) {
            float4 v = W[w_feat_base + (size_t)idxs[t] * 16 + lane];
            acc.x += v.x; acc.y += v.y; acc.z += v.z; acc.w += v.w;
        }
        const float inv = 1.0f / (float)max(cnt, 1);
        acc.x *= inv; acc.y *= inv; acc.z *= inv; acc.w *= inv;
        out[(size_t)tok * 16 + lane] = acc;
    }
}

extern "C" void kernel_launch(void* const* d_in, const int* in_sizes, int n_in,
                              void* d_out, int out_size, void* d_ws, size_t ws_size,
                              hipStream_t stream) {
    const int*    feats = (const int*)d_in[0];      // int_feats (BATCH, TOTAL_W)
    const float4* W     = (const float4*)d_in[1];   // W (N_FEAT, VOCAB+1, EMB)
    float4*       out   = (float4*)d_out;           // (BATCH, N_FEAT, EMB)

    const int tokens = BATCH * N_FEAT;              // 131072
    const int tokens_per_block = 256 / 16;          // 16
    const int grid = (tokens + tokens_per_block - 1) / tokens_per_block;  // 8192

    feb_kernel<<<grid, 256, 0, stream>>>(feats, W, out);
}